// Round 5
// baseline (276.898 us; speedup 1.0000x reference)
//
#include <hip/hip_runtime.h>
#include <hip/hip_bf16.h>
#include <math.h>

// Problem dims (fixed by reference)
#define BB 4
#define TT 1024
#define DD 1024
#define HPS 4          // heads per scale
#define C0 21
#define C1 41
#define N0 (HPS * C0)  // 84
#define N1 (HPS * C1)  // 164
#define NL 256         // padded combined logits width (84 + 164 = 248 -> 256)
#define BT (BB * TT)   // 4096
#define TB 64          // t-tile for window kernel
#define HALO 20
#define HB (TB + 2 * HALO)  // 104 rows staged
#define KSPLIT 2       // split-K for logits GEMM

typedef unsigned int uint;
typedef __bf16 bf16x8 __attribute__((ext_vector_type(8)));
typedef float f32x4 __attribute__((ext_vector_type(4)));

__device__ __forceinline__ ushort f2bf(float f) {
    union { float f; uint u; } v; v.f = f;
    uint u = v.u;
    uint r = (u + 0x7FFFu + ((u >> 16) & 1u)) >> 16;
    return (ushort)r;
}
__device__ __forceinline__ float bf2f(ushort s) {
    union { uint u; float f; } v; v.u = ((uint)s) << 16;
    return v.f;
}

// ---------------- fused conversion kernel ----------------
#define RQ  4096
#define R1  (RQ + 2048)
#define R2  (R1 + 1024)
#define R3  (R2 + 96)
#define R4  (R3 + 192)

__device__ __forceinline__ void transpose_tile(
    const float* __restrict__ in, ushort* __restrict__ out,
    int K, int Nin, int n_base, int Npad, int nx, int ky, int tid)
{
    __shared__ float tile[32][33];
    const int tx = tid & 31;
    const int ty = tid >> 5;   // 0..7
    const int n0 = nx * 32;
    const int k0 = ky * 32;
    #pragma unroll
    for (int i = 0; i < 4; i++) {
        int k = k0 + ty + i * 8;
        int n = n0 + tx;
        float v = (k < K && n < Nin) ? in[(size_t)k * Nin + n] : 0.0f;
        tile[ty + i * 8][tx] = v;
    }
    __syncthreads();
    #pragma unroll
    for (int i = 0; i < 4; i++) {
        int n = n0 + ty + i * 8;
        int k = k0 + tx;
        if (n < Npad && k < K)
            out[(size_t)(n_base + n) * K + k] = f2bf(tile[tx][ty + i * 8]);
    }
}

__global__ __launch_bounds__(256) void convert_all(
    const float* __restrict__ query, ushort* __restrict__ query_bf,
    const float* __restrict__ W_qv,  ushort* __restrict__ WqvT,
    const float* __restrict__ W_out, ushort* __restrict__ WoutT,
    const float* __restrict__ W2_0, const float* __restrict__ W2_1,
    ushort* __restrict__ W2T)
{
    const int blk = blockIdx.x;
    const int tid = threadIdx.x;
    if (blk < RQ) {
        int i = blk * 1024 + tid * 4;
        float4 v = *(const float4*)(query + i);
        ushort4 o;
        o.x = f2bf(v.x); o.y = f2bf(v.y); o.z = f2bf(v.z); o.w = f2bf(v.w);
        *(ushort4*)(query_bf + i) = o;
    } else if (blk < R1) {
        int idx = blk - RQ;                // 64 x 32
        transpose_tile(W_qv, WqvT, DD, 2 * DD, 0, 2 * DD, idx & 63, idx >> 6, tid);
    } else if (blk < R2) {
        int idx = blk - R1;                // 32 x 32
        transpose_tile(W_out, WoutT, DD, DD, 0, DD, idx & 31, idx >> 5, tid);
    } else if (blk < R3) {
        int idx = blk - R2;                // 3 x 32
        transpose_tile(W2_0, W2T, DD, N0, 0, N0, idx % 3, idx / 3, tid);
    } else {
        int idx = blk - R3;                // 6 x 32
        transpose_tile(W2_1, W2T, DD, N1, N0, NL - N0, idx % 6, idx / 6, tid);
    }
}

// ------------- barrier-free wave GEMM: 1 wave (64 thr) owns a 64x64 tile -------------
// A: [M][K] bf16 row-major. Bt: [N][K] bf16 row-major.
// Private double-buffered LDS; no __syncthreads anywhere.
// LDS layout per buffer: [kblk 0..3][row 0..63][8 ushort] (k-major, conflict-free).
// mode 0: Cf[row*ldc+col] = acc
// mode 2: col<DD -> Cb = bf16(relu(acc)); else Cv = bf16(acc)
// mode 3: Cf[(bz*BT + row)*ldc + col] = acc   (split-K partial)
__global__ __launch_bounds__(64) void gemm_wave(
    const ushort* __restrict__ A, const ushort* __restrict__ Bt,
    int K, int klen,
    float* __restrict__ Cf, ushort* __restrict__ Cb, ushort* __restrict__ Cv,
    int mode, int ldc)
{
    __shared__ ushort As[2][64 * 32];   // 2 x 4 KB
    __shared__ ushort Bs[2][64 * 32];   // 2 x 4 KB

    const int ln = threadIdx.x;         // 0..63
    const int row0 = blockIdx.y * 64;
    const int col0 = blockIdx.x * 64;
    const int kbase = blockIdx.z * klen;
    const int l15 = ln & 15;
    const int lq  = ln >> 4;            // 0..3

    f32x4 acc[4][4];
    #pragma unroll
    for (int i = 0; i < 4; i++)
        #pragma unroll
        for (int j = 0; j < 4; j++)
            acc[i][j] = (f32x4){0.f, 0.f, 0.f, 0.f};

    // lane ln stages row ln of A-tile / B-tile; one instr per 8-wide k-block.
    const ushort* gA = A  + (size_t)(row0 + ln) * K + kbase;
    const ushort* gB = Bt + (size_t)(col0 + ln) * K + kbase;

    // prologue: stage iter 0 into buffer 0
    #pragma unroll
    for (int kb = 0; kb < 4; kb++) {
        __builtin_amdgcn_global_load_lds(
            (const __attribute__((address_space(1))) void*)(gA + kb * 8),
            (__attribute__((address_space(3))) void*)(&As[0][kb * 512]), 16, 0, 0);
        __builtin_amdgcn_global_load_lds(
            (const __attribute__((address_space(1))) void*)(gB + kb * 8),
            (__attribute__((address_space(3))) void*)(&Bs[0][kb * 512]), 16, 0, 0);
    }

    const int iters = klen / 32;
    for (int it = 0; it < iters; it++) {
        const int buf = it & 1;
        // fragment reads (wave waits on its own vmcnt only — no barrier)
        bf16x8 af[4], bfr[4];
        #pragma unroll
        for (int mi = 0; mi < 4; mi++)
            af[mi] = *(const bf16x8*)&As[buf][lq * 512 + (mi * 16 + l15) * 8];
        #pragma unroll
        for (int ni = 0; ni < 4; ni++)
            bfr[ni] = *(const bf16x8*)&Bs[buf][lq * 512 + (ni * 16 + l15) * 8];

        // stage next iter into the other buffer (overlaps with MFMAs below)
        if (it + 1 < iters) {
            const int ko = (it + 1) * 32;
            #pragma unroll
            for (int kb = 0; kb < 4; kb++) {
                __builtin_amdgcn_global_load_lds(
                    (const __attribute__((address_space(1))) void*)(gA + ko + kb * 8),
                    (__attribute__((address_space(3))) void*)(&As[buf ^ 1][kb * 512]), 16, 0, 0);
                __builtin_amdgcn_global_load_lds(
                    (const __attribute__((address_space(1))) void*)(gB + ko + kb * 8),
                    (__attribute__((address_space(3))) void*)(&Bs[buf ^ 1][kb * 512]), 16, 0, 0);
            }
        }

        #pragma unroll
        for (int mi = 0; mi < 4; mi++)
            #pragma unroll
            for (int ni = 0; ni < 4; ni++)
                acc[mi][ni] = __builtin_amdgcn_mfma_f32_16x16x32_bf16(
                    af[mi], bfr[ni], acc[mi][ni], 0, 0, 0);
    }

    // Epilogue. D layout: col = lane&15, row = (lane>>4)*4 + reg.
    #pragma unroll
    for (int mi = 0; mi < 4; mi++) {
        #pragma unroll
        for (int ni = 0; ni < 4; ni++) {
            #pragma unroll
            for (int r = 0; r < 4; r++) {
                int row = row0 + mi * 16 + lq * 4 + r;
                int col = col0 + ni * 16 + l15;
                float v = acc[mi][ni][r];
                if (mode == 0) {
                    Cf[(size_t)row * ldc + col] = v;
                } else if (mode == 2) {
                    if (col < DD) Cb[(size_t)row * DD + col] = f2bf(fmaxf(v, 0.0f));
                    else          Cv[(size_t)row * DD + (col - DD)] = f2bf(v);
                } else {
                    Cf[((size_t)blockIdx.z * BT + row) * ldc + col] = v;
                }
            }
        }
    }
}

// ------------- Tiled window kernel: block = (b, t-tile of 64, head) -------------
__global__ __launch_bounds__(256) void attn_window_kernel(
    const ushort* __restrict__ v,
    const float* __restrict__ Lp,
    const float* __restrict__ scale_w,
    ushort* __restrict__ x)
{
    const int blk = blockIdx.x;       // 256 blocks
    const int h  = blk & 3;
    const int tt = (blk >> 2) & 15;
    const int b  = blk >> 6;
    const int t0 = tt * TB;
    const int tid = threadIdx.x;
    const size_t PS = (size_t)BT * NL; // partial stride

    __shared__ ushort vs[HB][256];    // 53,248 B
    __shared__ float  cw[TB][42];

    const ushort* vb = v + (size_t)b * TT * DD + h * 256;
    #pragma unroll
    for (int i = 0; i < 13; i++) {
        int c = i * 256 + tid;
        int r = c >> 5;
        int cir = c & 31;
        int t = t0 - HALO + r;
        uint4 val = make_uint4(0, 0, 0, 0);
        if (t >= 0 && t < TT)
            val = *(const uint4*)(vb + (size_t)t * DD + cir * 8);
        *(uint4*)(&vs[r][cir * 8]) = val;
    }

    if (tid < TB) {
        const int bt = b * TT + t0 + tid;
        const float* Lb = Lp + (size_t)bt * NL;

        float s0 = scale_w[0], s1 = scale_w[1];
        float mm = fmaxf(s0, s1);
        float e0 = __expf(s0 - mm), e1 = __expf(s1 - mm);
        float inv01 = 1.0f / (e0 + e1);
        float sw0 = e0 * inv01, sw1 = e1 * inv01;

        float w0[C0], w1[C1];
        {
            const int off = h * C0;
            float m = -1e30f;
            #pragma unroll
            for (int j = 0; j < C0; j++) {
                w0[j] = Lb[off + j] + Lb[PS + off + j];
                m = fmaxf(m, w0[j]);
            }
            float s = 0.0f;
            #pragma unroll
            for (int j = 0; j < C0; j++) { w0[j] = __expf(w0[j] - m); s += w0[j]; }
            float inv = sw0 / s;
            #pragma unroll
            for (int j = 0; j < C0; j++) w0[j] *= inv;
        }
        {
            const int off = N0 + h * C1;
            float m = -1e30f;
            #pragma unroll
            for (int j = 0; j < C1; j++) {
                w1[j] = Lb[off + j] + Lb[PS + off + j];
                m = fmaxf(m, w1[j]);
            }
            float s = 0.0f;
            #pragma unroll
            for (int j = 0; j < C1; j++) { w1[j] = __expf(w1[j] - m); s += w1[j]; }
            float inv = sw1 / s;
            #pragma unroll
            for (int j = 0; j < C1; j++) w1[j] *= inv;
        }
        #pragma unroll
        for (int o = 0; o < C1; o++) {
            float w = w1[o];
            if (o >= 10 && o <= 30) w += w0[o - 10];
            cw[tid][o] = w;
        }
    }
    __syncthreads();

    const int tq = tid >> 6;
    const int dg = tid & 63;
    const int d  = dg * 4;

    for (int tloc = 0; tloc < 16; tloc++) {
        const int tp = tq * 16 + tloc;
        f32x4 acc = {0.f, 0.f, 0.f, 0.f};
        #pragma unroll
        for (int o = 0; o < C1; o++) {
            float w = cw[tp][o];
            ushort4 vv = *(const ushort4*)(&vs[tp + o][d]);
            acc[0] = fmaf(w, bf2f(vv.x), acc[0]);
            acc[1] = fmaf(w, bf2f(vv.y), acc[1]);
            acc[2] = fmaf(w, bf2f(vv.z), acc[2]);
            acc[3] = fmaf(w, bf2f(vv.w), acc[3]);
        }
        const int bt = b * TT + t0 + tp;
        ushort4 o4;
        o4.x = f2bf(acc[0]); o4.y = f2bf(acc[1]);
        o4.z = f2bf(acc[2]); o4.w = f2bf(acc[3]);
        *(ushort4*)(x + (size_t)bt * DD + h * 256 + d) = o4;
    }
}

// ---------------------------------- launch ----------------------------------
extern "C" void kernel_launch(void* const* d_in, const int* in_sizes, int n_in,
                              void* d_out, int out_size, void* d_ws, size_t ws_size,
                              hipStream_t stream)
{
    const float* query   = (const float*)d_in[0];
    const float* W_qv    = (const float*)d_in[3];
    const float* W2_0    = (const float*)d_in[4];
    const float* W2_1    = (const float*)d_in[5];
    const float* scale_w = (const float*)d_in[6];
    const float* W_out   = (const float*)d_in[7];
    float* out = (float*)d_out;

    // Workspace layout. logitsP aliases query_bf (dead by the time logits GEMM runs).
    char* ws = (char*)d_ws;
    ushort* W2T      = (ushort*)ws;                 ws += (size_t)NL * DD * 2;        // 0.5 MB
    ushort* WoutT    = (ushort*)ws;                 ws += (size_t)DD * DD * 2;        // 2 MB
    ushort* query_bf = (ushort*)ws;
    float*  logitsP  = (float*)ws;                  ws += (size_t)BT * DD * 2;        // 8 MB
    ushort* WqvT     = (ushort*)ws;                 ws += (size_t)2 * DD * DD * 2;    // 4 MB
    ushort* reluq    = (ushort*)ws;                 ws += (size_t)BT * DD * 2;        // 8 MB
    ushort* vbuf     = (ushort*)ws;                 ws += (size_t)BT * DD * 2;        // 8 MB
    ushort* xbuf     = (ushort*)ws;                 ws += (size_t)BT * DD * 2;        // 8 MB

    // 0) all conversions in one launch
    convert_all<<<R4, 256, 0, stream>>>(query, query_bf, W_qv, WqvT,
                                        W_out, WoutT, W2_0, W2_1, W2T);

    // 1) qv GEMM: [4096,1024]x[1024,2048] -> reluq bf16 + v bf16 (2048 wave-blocks)
    {   dim3 grid(2 * DD / 64, BT / 64, 1);
        gemm_wave<<<grid, 64, 0, stream>>>(query_bf, WqvT, DD, DD,
                                           nullptr, reluq, vbuf, 2, 0); }
    // 2) logits GEMM split-K=2: relu(q) x W2T -> logitsP (512 wave-blocks)
    {   dim3 grid(NL / 64, BT / 64, KSPLIT);
        gemm_wave<<<grid, 64, 0, stream>>>(reluq, W2T, DD, DD / KSPLIT,
                                           logitsP, nullptr, nullptr, 3, NL); }
    // 3) softmax (+partial sum) + sliding window -> xbuf bf16
    attn_window_kernel<<<256, 256, 0, stream>>>(vbuf, logitsP, scale_w, xbuf);

    // 4) out GEMM: x x WoutT -> out f32 (1024 wave-blocks)
    {   dim3 grid(DD / 64, BT / 64, 1);
        gemm_wave<<<grid, 64, 0, stream>>>(xbuf, WoutT, DD, DD,
                                           out, nullptr, nullptr, 0, DD); }
}

// Round 6
// 232.679 us; speedup vs baseline: 1.1900x; 1.1900x over previous
//
#include <hip/hip_runtime.h>
#include <hip/hip_bf16.h>
#include <math.h>

// Problem dims (fixed by reference)
#define BB 4
#define TT 1024
#define DD 1024
#define HPS 4          // heads per scale
#define C0 21
#define C1 41
#define N0 (HPS * C0)  // 84
#define N1 (HPS * C1)  // 164
#define NL 256         // padded combined logits width (84 + 164 = 248 -> 256)
#define BT (BB * TT)   // 4096
#define TB 64          // t-tile for window kernel
#define HALO 20
#define HB (TB + 2 * HALO)  // 104 rows staged
#define KSPLIT 2       // split-K for logits GEMM

typedef unsigned int uint;
typedef __bf16 bf16x8 __attribute__((ext_vector_type(8)));
typedef float f32x4 __attribute__((ext_vector_type(4)));

__device__ __forceinline__ ushort f2bf(float f) {
    union { float f; uint u; } v; v.f = f;
    uint u = v.u;
    uint r = (u + 0x7FFFu + ((u >> 16) & 1u)) >> 16;
    return (ushort)r;
}
__device__ __forceinline__ float bf2f(ushort s) {
    union { uint u; float f; } v; v.u = ((uint)s) << 16;
    return v.f;
}

// ---------------- fused conversion kernel ----------------
#define RQ  4096
#define R1  (RQ + 2048)
#define R2  (R1 + 1024)
#define R3  (R2 + 96)
#define R4  (R3 + 192)

__device__ __forceinline__ void transpose_tile(
    const float* __restrict__ in, ushort* __restrict__ out,
    int K, int Nin, int n_base, int Npad, int nx, int ky, int tid)
{
    __shared__ float tile[32][33];
    const int tx = tid & 31;
    const int ty = tid >> 5;   // 0..7
    const int n0 = nx * 32;
    const int k0 = ky * 32;
    #pragma unroll
    for (int i = 0; i < 4; i++) {
        int k = k0 + ty + i * 8;
        int n = n0 + tx;
        float v = (k < K && n < Nin) ? in[(size_t)k * Nin + n] : 0.0f;
        tile[ty + i * 8][tx] = v;
    }
    __syncthreads();
    #pragma unroll
    for (int i = 0; i < 4; i++) {
        int n = n0 + ty + i * 8;
        int k = k0 + tx;
        if (n < Npad && k < K)
            out[(size_t)(n_base + n) * K + k] = f2bf(tile[tx][ty + i * 8]);
    }
}

__global__ __launch_bounds__(256) void convert_all(
    const float* __restrict__ query, ushort* __restrict__ query_bf,
    const float* __restrict__ W_qv,  ushort* __restrict__ WqvT,
    const float* __restrict__ W_out, ushort* __restrict__ WoutT,
    const float* __restrict__ W2_0, const float* __restrict__ W2_1,
    ushort* __restrict__ W2T)
{
    const int blk = blockIdx.x;
    const int tid = threadIdx.x;
    if (blk < RQ) {
        int i = blk * 1024 + tid * 4;
        float4 v = *(const float4*)(query + i);
        ushort4 o;
        o.x = f2bf(v.x); o.y = f2bf(v.y); o.z = f2bf(v.z); o.w = f2bf(v.w);
        *(ushort4*)(query_bf + i) = o;
    } else if (blk < R1) {
        int idx = blk - RQ;                // 64 x 32
        transpose_tile(W_qv, WqvT, DD, 2 * DD, 0, 2 * DD, idx & 63, idx >> 6, tid);
    } else if (blk < R2) {
        int idx = blk - R1;                // 32 x 32
        transpose_tile(W_out, WoutT, DD, DD, 0, DD, idx & 31, idx >> 5, tid);
    } else if (blk < R3) {
        int idx = blk - R2;                // 3 x 32
        transpose_tile(W2_0, W2T, DD, N0, 0, N0, idx % 3, idx / 3, tid);
    } else {
        int idx = blk - R3;                // 6 x 32
        transpose_tile(W2_1, W2T, DD, N1, N0, NL - N0, idx % 6, idx / 6, tid);
    }
}

// -------- bf16 MFMA GEMM, 128x128 tile, BK=128, k-major LDS, 2-barrier --------
// A: [M][K] bf16 row-major. Bt: [N][K] bf16 row-major.
// LDS layout: [kblk 0..15][row 0..127][8 ushort]; conflict-free ds_read_b128,
// and global_load_lds dest = wave-uniform base + lane*16 (HW adds lane offset).
// K and klen must be multiples of 128.
// mode 0: Cf[row*ldc+col] = acc
// mode 2: col<DD -> Cb = bf16(relu(acc)); else Cv = bf16(acc)
// mode 3: Cf[(bz*BT + row)*ldc + col] = acc   (split-K partial)
__global__ __launch_bounds__(256) void gemm_mfma(
    const ushort* __restrict__ A, const ushort* __restrict__ Bt,
    int K, int klen,
    float* __restrict__ Cf, ushort* __restrict__ Cb, ushort* __restrict__ Cv,
    int mode, int ldc)
{
    __shared__ ushort As[16 * 128 * 8];   // 32 KB
    __shared__ ushort Bs[16 * 128 * 8];   // 32 KB  (total 64 KB = static max)

    const int tid = threadIdx.x;
    const int wv  = tid >> 6;         // wave 0..3
    const int ln  = tid & 63;
    const int row0 = blockIdx.y * 128;
    const int col0 = blockIdx.x * 128;
    const int kbase = blockIdx.z * klen;
    const int wr = (wv >> 1) * 64;
    const int wc = (wv & 1) * 64;
    const int l15 = ln & 15;
    const int lq  = ln >> 4;          // 0..3

    f32x4 acc[4][4];
    #pragma unroll
    for (int i = 0; i < 4; i++)
        #pragma unroll
        for (int j = 0; j < 4; j++)
            acc[i][j] = (f32x4){0.f, 0.f, 0.f, 0.f};

    // staging: thread tid handles row (tid&127), kblks {2i + (tid>>7)}, i=0..7
    const int srow = tid & 127;
    const int kb0  = tid >> 7;        // 0 or 1
    const ushort* gA = A  + (size_t)(row0 + srow) * K + kbase + kb0 * 8;
    const ushort* gB = Bt + (size_t)(col0 + srow) * K + kbase + kb0 * 8;

    for (int k0 = 0; k0 < klen; k0 += 128) {
        __syncthreads();   // LDS free (previous iter's ds_reads done)
        #pragma unroll
        for (int i = 0; i < 8; i++) {
            __builtin_amdgcn_global_load_lds(
                (const __attribute__((address_space(1))) void*)(gA + k0 + i * 16),
                (__attribute__((address_space(3))) void*)(As + i * 2048 + wv * 512),
                16, 0, 0);
        }
        #pragma unroll
        for (int i = 0; i < 8; i++) {
            __builtin_amdgcn_global_load_lds(
                (const __attribute__((address_space(1))) void*)(gB + k0 + i * 16),
                (__attribute__((address_space(3))) void*)(Bs + i * 2048 + wv * 512),
                16, 0, 0);
        }
        __syncthreads();   // compiler drains vmcnt here (loads visible in LDS)

        #pragma unroll
        for (int s = 0; s < 4; s++) {
            bf16x8 af[4], bfr[4];
            #pragma unroll
            for (int mi = 0; mi < 4; mi++)
                af[mi] = *(const bf16x8*)&As[(s * 4 + lq) * 1024 + (wr + mi * 16 + l15) * 8];
            #pragma unroll
            for (int ni = 0; ni < 4; ni++)
                bfr[ni] = *(const bf16x8*)&Bs[(s * 4 + lq) * 1024 + (wc + ni * 16 + l15) * 8];
            #pragma unroll
            for (int mi = 0; mi < 4; mi++)
                #pragma unroll
                for (int ni = 0; ni < 4; ni++)
                    acc[mi][ni] = __builtin_amdgcn_mfma_f32_16x16x32_bf16(
                        af[mi], bfr[ni], acc[mi][ni], 0, 0, 0);
        }
    }

    // Epilogue. D layout: col = lane&15, row = (lane>>4)*4 + reg.
    #pragma unroll
    for (int mi = 0; mi < 4; mi++) {
        #pragma unroll
        for (int ni = 0; ni < 4; ni++) {
            #pragma unroll
            for (int r = 0; r < 4; r++) {
                int row = row0 + wr + mi * 16 + lq * 4 + r;
                int col = col0 + wc + ni * 16 + l15;
                float v = acc[mi][ni][r];
                if (mode == 0) {
                    Cf[(size_t)row * ldc + col] = v;
                } else if (mode == 2) {
                    if (col < DD) Cb[(size_t)row * DD + col] = f2bf(fmaxf(v, 0.0f));
                    else          Cv[(size_t)row * DD + (col - DD)] = f2bf(v);
                } else {
                    Cf[((size_t)blockIdx.z * BT + row) * ldc + col] = v;
                }
            }
        }
    }
}

// ------------- Tiled window kernel: block = (b, t-tile of 64, head) -------------
__global__ __launch_bounds__(256) void attn_window_kernel(
    const ushort* __restrict__ v,
    const float* __restrict__ Lp,
    const float* __restrict__ scale_w,
    ushort* __restrict__ x)
{
    const int blk = blockIdx.x;       // 256 blocks
    const int h  = blk & 3;
    const int tt = (blk >> 2) & 15;
    const int b  = blk >> 6;
    const int t0 = tt * TB;
    const int tid = threadIdx.x;
    const size_t PS = (size_t)BT * NL; // partial stride

    __shared__ ushort vs[HB][256];    // 53,248 B
    __shared__ float  cw[TB][42];

    const ushort* vb = v + (size_t)b * TT * DD + h * 256;
    #pragma unroll
    for (int i = 0; i < 13; i++) {
        int c = i * 256 + tid;
        int r = c >> 5;
        int cir = c & 31;
        int t = t0 - HALO + r;
        uint4 val = make_uint4(0, 0, 0, 0);
        if (t >= 0 && t < TT)
            val = *(const uint4*)(vb + (size_t)t * DD + cir * 8);
        *(uint4*)(&vs[r][cir * 8]) = val;
    }

    if (tid < TB) {
        const int bt = b * TT + t0 + tid;
        const float* Lb = Lp + (size_t)bt * NL;

        float s0 = scale_w[0], s1 = scale_w[1];
        float mm = fmaxf(s0, s1);
        float e0 = __expf(s0 - mm), e1 = __expf(s1 - mm);
        float inv01 = 1.0f / (e0 + e1);
        float sw0 = e0 * inv01, sw1 = e1 * inv01;

        float w0[C0], w1[C1];
        {
            const int off = h * C0;
            float m = -1e30f;
            #pragma unroll
            for (int j = 0; j < C0; j++) {
                w0[j] = Lb[off + j] + Lb[PS + off + j];
                m = fmaxf(m, w0[j]);
            }
            float s = 0.0f;
            #pragma unroll
            for (int j = 0; j < C0; j++) { w0[j] = __expf(w0[j] - m); s += w0[j]; }
            float inv = sw0 / s;
            #pragma unroll
            for (int j = 0; j < C0; j++) w0[j] *= inv;
        }
        {
            const int off = N0 + h * C1;
            float m = -1e30f;
            #pragma unroll
            for (int j = 0; j < C1; j++) {
                w1[j] = Lb[off + j] + Lb[PS + off + j];
                m = fmaxf(m, w1[j]);
            }
            float s = 0.0f;
            #pragma unroll
            for (int j = 0; j < C1; j++) { w1[j] = __expf(w1[j] - m); s += w1[j]; }
            float inv = sw1 / s;
            #pragma unroll
            for (int j = 0; j < C1; j++) w1[j] *= inv;
        }
        #pragma unroll
        for (int o = 0; o < C1; o++) {
            float w = w1[o];
            if (o >= 10 && o <= 30) w += w0[o - 10];
            cw[tid][o] = w;
        }
    }
    __syncthreads();

    const int tq = tid >> 6;
    const int dg = tid & 63;
    const int d  = dg * 4;

    for (int tloc = 0; tloc < 16; tloc++) {
        const int tp = tq * 16 + tloc;
        f32x4 acc = {0.f, 0.f, 0.f, 0.f};
        #pragma unroll
        for (int o = 0; o < C1; o++) {
            float w = cw[tp][o];
            ushort4 vv = *(const ushort4*)(&vs[tp + o][d]);
            acc[0] = fmaf(w, bf2f(vv.x), acc[0]);
            acc[1] = fmaf(w, bf2f(vv.y), acc[1]);
            acc[2] = fmaf(w, bf2f(vv.z), acc[2]);
            acc[3] = fmaf(w, bf2f(vv.w), acc[3]);
        }
        const int bt = b * TT + t0 + tp;
        ushort4 o4;
        o4.x = f2bf(acc[0]); o4.y = f2bf(acc[1]);
        o4.z = f2bf(acc[2]); o4.w = f2bf(acc[3]);
        *(ushort4*)(x + (size_t)bt * DD + h * 256 + d) = o4;
    }
}

// ---------------------------------- launch ----------------------------------
extern "C" void kernel_launch(void* const* d_in, const int* in_sizes, int n_in,
                              void* d_out, int out_size, void* d_ws, size_t ws_size,
                              hipStream_t stream)
{
    const float* query   = (const float*)d_in[0];
    const float* W_qv    = (const float*)d_in[3];
    const float* W2_0    = (const float*)d_in[4];
    const float* W2_1    = (const float*)d_in[5];
    const float* scale_w = (const float*)d_in[6];
    const float* W_out   = (const float*)d_in[7];
    float* out = (float*)d_out;

    // Workspace layout. logitsP (8 MB) aliases query_bf (dead after qv GEMM).
    char* ws = (char*)d_ws;
    ushort* W2T      = (ushort*)ws;                 ws += (size_t)NL * DD * 2;        // 0.5 MB
    ushort* WoutT    = (ushort*)ws;                 ws += (size_t)DD * DD * 2;        // 2 MB
    ushort* query_bf = (ushort*)ws;
    float*  logitsP  = (float*)ws;                  ws += (size_t)BT * DD * 2;        // 8 MB
    ushort* WqvT     = (ushort*)ws;                 ws += (size_t)2 * DD * DD * 2;    // 4 MB
    ushort* reluq    = (ushort*)ws;                 ws += (size_t)BT * DD * 2;        // 8 MB
    ushort* vbuf     = (ushort*)ws;                 ws += (size_t)BT * DD * 2;        // 8 MB
    ushort* xbuf     = (ushort*)ws;                 ws += (size_t)BT * DD * 2;        // 8 MB

    // 0) all conversions in one launch
    convert_all<<<R4, 256, 0, stream>>>(query, query_bf, W_qv, WqvT,
                                        W_out, WoutT, W2_0, W2_1, W2T);

    // 1) qv GEMM: [4096,1024]x[1024,2048] -> reluq bf16 + v bf16 (512 blocks, 8 iters)
    {   dim3 grid(2 * DD / 128, BT / 128, 1);
        gemm_mfma<<<grid, 256, 0, stream>>>(query_bf, WqvT, DD, DD,
                                            nullptr, reluq, vbuf, 2, 0); }
    // 2) logits GEMM split-K=2: relu(q) x W2T -> logitsP (128 blocks, 4 iters)
    {   dim3 grid(NL / 128, BT / 128, KSPLIT);
        gemm_mfma<<<grid, 256, 0, stream>>>(reluq, W2T, DD, DD / KSPLIT,
                                            logitsP, nullptr, nullptr, 3, NL); }
    // 3) softmax (+partial sum) + sliding window -> xbuf bf16
    attn_window_kernel<<<256, 256, 0, stream>>>(vbuf, logitsP, scale_w, xbuf);

    // 4) out GEMM: x x WoutT -> out f32 (256 blocks, 8 iters)
    {   dim3 grid(DD / 128, BT / 128, 1);
        gemm_mfma<<<grid, 256, 0, stream>>>(xbuf, WoutT, DD, DD,
                                            out, nullptr, nullptr, 0, DD); }
}

// Round 7
// 199.082 us; speedup vs baseline: 1.3909x; 1.1688x over previous
//
#include <hip/hip_runtime.h>
#include <hip/hip_bf16.h>
#include <math.h>

// Problem dims (fixed by reference)
#define BB 4
#define TT 1024
#define DD 1024
#define HPS 4          // heads per scale
#define C0 21
#define C1 41
#define N0 (HPS * C0)  // 84
#define N1 (HPS * C1)  // 164
#define NL 256         // padded combined logits width (84 + 164 = 248 -> 256)
#define BT (BB * TT)   // 4096
#define TB 64          // t-tile for window kernel
#define HALO 20
#define HB (TB + 2 * HALO)  // 104 rows staged
#define KSPLIT 2       // split-K for logits GEMM

typedef unsigned int uint;
typedef __bf16 bf16x8 __attribute__((ext_vector_type(8)));
typedef float f32x4 __attribute__((ext_vector_type(4)));

__device__ __forceinline__ ushort f2bf(float f) {
    union { float f; uint u; } v; v.f = f;
    uint u = v.u;
    uint r = (u + 0x7FFFu + ((u >> 16) & 1u)) >> 16;
    return (ushort)r;
}
__device__ __forceinline__ float bf2f(ushort s) {
    union { uint u; float f; } v; v.u = ((uint)s) << 16;
    return v.f;
}

// ---------------- fused conversion kernel ----------------
#define RQ  4096
#define R1  (RQ + 2048)
#define R2  (R1 + 1024)
#define R3  (R2 + 96)
#define R4  (R3 + 192)

__device__ __forceinline__ void transpose_tile(
    const float* __restrict__ in, ushort* __restrict__ out,
    int K, int Nin, int n_base, int Npad, int nx, int ky, int tid)
{
    __shared__ float tile[32][33];
    const int tx = tid & 31;
    const int ty = tid >> 5;   // 0..7
    const int n0 = nx * 32;
    const int k0 = ky * 32;
    #pragma unroll
    for (int i = 0; i < 4; i++) {
        int k = k0 + ty + i * 8;
        int n = n0 + tx;
        float v = (k < K && n < Nin) ? in[(size_t)k * Nin + n] : 0.0f;
        tile[ty + i * 8][tx] = v;
    }
    __syncthreads();
    #pragma unroll
    for (int i = 0; i < 4; i++) {
        int n = n0 + ty + i * 8;
        int k = k0 + tx;
        if (n < Npad && k < K)
            out[(size_t)(n_base + n) * K + k] = f2bf(tile[tx][ty + i * 8]);
    }
}

__global__ __launch_bounds__(256) void convert_all(
    const float* __restrict__ query, ushort* __restrict__ query_bf,
    const float* __restrict__ W_qv,  ushort* __restrict__ WqvT,
    const float* __restrict__ W_out, ushort* __restrict__ WoutT,
    const float* __restrict__ W2_0, const float* __restrict__ W2_1,
    ushort* __restrict__ W2T)
{
    const int blk = blockIdx.x;
    const int tid = threadIdx.x;
    if (blk < RQ) {
        int i = blk * 1024 + tid * 4;
        float4 v = *(const float4*)(query + i);
        ushort4 o;
        o.x = f2bf(v.x); o.y = f2bf(v.y); o.z = f2bf(v.z); o.w = f2bf(v.w);
        *(ushort4*)(query_bf + i) = o;
    } else if (blk < R1) {
        int idx = blk - RQ;                // 64 x 32
        transpose_tile(W_qv, WqvT, DD, 2 * DD, 0, 2 * DD, idx & 63, idx >> 6, tid);
    } else if (blk < R2) {
        int idx = blk - R1;                // 32 x 32
        transpose_tile(W_out, WoutT, DD, DD, 0, DD, idx & 31, idx >> 5, tid);
    } else if (blk < R3) {
        int idx = blk - R2;                // 3 x 32
        transpose_tile(W2_0, W2T, DD, N0, 0, N0, idx % 3, idx / 3, tid);
    } else {
        int idx = blk - R3;                // 6 x 32
        transpose_tile(W2_1, W2T, DD, N1, N0, NL - N0, idx % 6, idx / 6, tid);
    }
}

// -------- bf16 MFMA GEMM, 128x128 tile, BK=128, swizzled row-major LDS --------
// A: [M][K] bf16 row-major. Bt: [N][K] bf16 row-major.
// LDS: [row 0..127][chunk 0..15][8 ushort]; slot (r,c) holds global chunk c^(r&7).
// Staging: wave-instr covers 4 rows x 256 B contiguous (16 full cache lines);
// fragment ds_read_b128 spreads 16 lanes over 8 bank-quads (2-way = free).
// K, klen multiples of 128.
// mode 0: Cf[row*ldc+col] = acc
// mode 2: col<DD -> Cb = bf16(relu(acc)); else Cv = bf16(acc)
// mode 3: Cf[(bz*BT + row)*ldc + col] = acc   (split-K partial)
__global__ __launch_bounds__(256) void gemm_mfma(
    const ushort* __restrict__ A, const ushort* __restrict__ Bt,
    int K, int klen,
    float* __restrict__ Cf, ushort* __restrict__ Cb, ushort* __restrict__ Cv,
    int mode, int ldc)
{
    __shared__ ushort As[128 * 128];   // 32 KB
    __shared__ ushort Bs[128 * 128];   // 32 KB (total 64 KB)

    const int tid = threadIdx.x;
    const int wv  = tid >> 6;         // wave 0..3
    const int ln  = tid & 63;
    const int row0 = blockIdx.y * 128;
    const int col0 = blockIdx.x * 128;
    const int kbase = blockIdx.z * klen;
    const int wr = (wv >> 1) * 64;
    const int wc = (wv & 1) * 64;
    const int l15 = ln & 15;
    const int lq  = ln >> 4;          // 0..3

    f32x4 acc[4][4];
    #pragma unroll
    for (int i = 0; i < 4; i++)
        #pragma unroll
        for (int j = 0; j < 4; j++)
            acc[i][j] = (f32x4){0.f, 0.f, 0.f, 0.f};

    // staging: instr i, wave wv covers rows i*16 + wv*4 + (ln>>4), chunk ln&15.
    // global chunk fetched = slot ^ (row&7); row&7 is instr-invariant.
    const int r_lo = wv * 4 + (ln >> 4);            // 0..15
    const int cc   = (ln & 15) ^ (r_lo & 7);        // global chunk for this lane
    const ushort* gA = A  + (size_t)(row0 + r_lo) * K + kbase + cc * 8;
    const ushort* gB = Bt + (size_t)(col0 + r_lo) * K + kbase + cc * 8;

    const int fx = l15 & 7;           // fragment-read xor

    for (int k0 = 0; k0 < klen; k0 += 128) {
        __syncthreads();   // previous iter's ds_reads done, LDS free
        #pragma unroll
        for (int i = 0; i < 8; i++) {
            __builtin_amdgcn_global_load_lds(
                (const __attribute__((address_space(1))) void*)(gA + (size_t)i * 16 * K + k0),
                (__attribute__((address_space(3))) void*)(As + i * 2048 + wv * 512),
                16, 0, 0);
        }
        #pragma unroll
        for (int i = 0; i < 8; i++) {
            __builtin_amdgcn_global_load_lds(
                (const __attribute__((address_space(1))) void*)(gB + (size_t)i * 16 * K + k0),
                (__attribute__((address_space(3))) void*)(Bs + i * 2048 + wv * 512),
                16, 0, 0);
        }
        __syncthreads();   // compiler drains vmcnt (loads visible in LDS)

        #pragma unroll
        for (int s = 0; s < 4; s++) {
            const int ca = ((s * 4 + lq) ^ fx) * 8;
            bf16x8 af[4], bfr[4];
            #pragma unroll
            for (int mi = 0; mi < 4; mi++)
                af[mi] = *(const bf16x8*)&As[(wr + mi * 16 + l15) * 128 + ca];
            #pragma unroll
            for (int ni = 0; ni < 4; ni++)
                bfr[ni] = *(const bf16x8*)&Bs[(wc + ni * 16 + l15) * 128 + ca];
            #pragma unroll
            for (int mi = 0; mi < 4; mi++)
                #pragma unroll
                for (int ni = 0; ni < 4; ni++)
                    acc[mi][ni] = __builtin_amdgcn_mfma_f32_16x16x32_bf16(
                        af[mi], bfr[ni], acc[mi][ni], 0, 0, 0);
        }
    }

    // Epilogue. D layout: col = lane&15, row = (lane>>4)*4 + reg.
    #pragma unroll
    for (int mi = 0; mi < 4; mi++) {
        #pragma unroll
        for (int ni = 0; ni < 4; ni++) {
            #pragma unroll
            for (int r = 0; r < 4; r++) {
                int row = row0 + wr + mi * 16 + lq * 4 + r;
                int col = col0 + wc + ni * 16 + l15;
                float v = acc[mi][ni][r];
                if (mode == 0) {
                    Cf[(size_t)row * ldc + col] = v;
                } else if (mode == 2) {
                    if (col < DD) Cb[(size_t)row * DD + col] = f2bf(fmaxf(v, 0.0f));
                    else          Cv[(size_t)row * DD + (col - DD)] = f2bf(v);
                } else {
                    Cf[((size_t)blockIdx.z * BT + row) * ldc + col] = v;
                }
            }
        }
    }
}

// ------------- Tiled window kernel: block = (b, t-tile of 64, head) -------------
__global__ __launch_bounds__(256) void attn_window_kernel(
    const ushort* __restrict__ v,
    const float* __restrict__ Lp,
    const float* __restrict__ scale_w,
    ushort* __restrict__ x)
{
    const int blk = blockIdx.x;       // 256 blocks
    const int h  = blk & 3;
    const int tt = (blk >> 2) & 15;
    const int b  = blk >> 6;
    const int t0 = tt * TB;
    const int tid = threadIdx.x;
    const size_t PS = (size_t)BT * NL; // partial stride

    __shared__ ushort vs[HB][256];    // 53,248 B
    __shared__ float  cw[TB][42];

    const ushort* vb = v + (size_t)b * TT * DD + h * 256;
    #pragma unroll
    for (int i = 0; i < 13; i++) {
        int c = i * 256 + tid;
        int r = c >> 5;
        int cir = c & 31;
        int t = t0 - HALO + r;
        uint4 val = make_uint4(0, 0, 0, 0);
        if (t >= 0 && t < TT)
            val = *(const uint4*)(vb + (size_t)t * DD + cir * 8);
        *(uint4*)(&vs[r][cir * 8]) = val;
    }

    if (tid < TB) {
        const int bt = b * TT + t0 + tid;
        const float* Lb = Lp + (size_t)bt * NL;

        float s0 = scale_w[0], s1 = scale_w[1];
        float mm = fmaxf(s0, s1);
        float e0 = __expf(s0 - mm), e1 = __expf(s1 - mm);
        float inv01 = 1.0f / (e0 + e1);
        float sw0 = e0 * inv01, sw1 = e1 * inv01;

        float w0[C0], w1[C1];
        {
            const int off = h * C0;
            float m = -1e30f;
            #pragma unroll
            for (int j = 0; j < C0; j++) {
                w0[j] = Lb[off + j] + Lb[PS + off + j];
                m = fmaxf(m, w0[j]);
            }
            float s = 0.0f;
            #pragma unroll
            for (int j = 0; j < C0; j++) { w0[j] = __expf(w0[j] - m); s += w0[j]; }
            float inv = sw0 / s;
            #pragma unroll
            for (int j = 0; j < C0; j++) w0[j] *= inv;
        }
        {
            const int off = N0 + h * C1;
            float m = -1e30f;
            #pragma unroll
            for (int j = 0; j < C1; j++) {
                w1[j] = Lb[off + j] + Lb[PS + off + j];
                m = fmaxf(m, w1[j]);
            }
            float s = 0.0f;
            #pragma unroll
            for (int j = 0; j < C1; j++) { w1[j] = __expf(w1[j] - m); s += w1[j]; }
            float inv = sw1 / s;
            #pragma unroll
            for (int j = 0; j < C1; j++) w1[j] *= inv;
        }
        #pragma unroll
        for (int o = 0; o < C1; o++) {
            float w = w1[o];
            if (o >= 10 && o <= 30) w += w0[o - 10];
            cw[tid][o] = w;
        }
    }
    __syncthreads();

    const int tq = tid >> 6;
    const int dg = tid & 63;
    const int d  = dg * 4;

    for (int tloc = 0; tloc < 16; tloc++) {
        const int tp = tq * 16 + tloc;
        f32x4 acc = {0.f, 0.f, 0.f, 0.f};
        #pragma unroll
        for (int o = 0; o < C1; o++) {
            float w = cw[tp][o];
            ushort4 vv = *(const ushort4*)(&vs[tp + o][d]);
            acc[0] = fmaf(w, bf2f(vv.x), acc[0]);
            acc[1] = fmaf(w, bf2f(vv.y), acc[1]);
            acc[2] = fmaf(w, bf2f(vv.z), acc[2]);
            acc[3] = fmaf(w, bf2f(vv.w), acc[3]);
        }
        const int bt = b * TT + t0 + tp;
        ushort4 o4;
        o4.x = f2bf(acc[0]); o4.y = f2bf(acc[1]);
        o4.z = f2bf(acc[2]); o4.w = f2bf(acc[3]);
        *(ushort4*)(x + (size_t)bt * DD + h * 256 + d) = o4;
    }
}

// ---------------------------------- launch ----------------------------------
extern "C" void kernel_launch(void* const* d_in, const int* in_sizes, int n_in,
                              void* d_out, int out_size, void* d_ws, size_t ws_size,
                              hipStream_t stream)
{
    const float* query   = (const float*)d_in[0];
    const float* W_qv    = (const float*)d_in[3];
    const float* W2_0    = (const float*)d_in[4];
    const float* W2_1    = (const float*)d_in[5];
    const float* scale_w = (const float*)d_in[6];
    const float* W_out   = (const float*)d_in[7];
    float* out = (float*)d_out;

    // Workspace layout. logitsP (8 MB) aliases query_bf (dead after qv GEMM).
    char* ws = (char*)d_ws;
    ushort* W2T      = (ushort*)ws;                 ws += (size_t)NL * DD * 2;        // 0.5 MB
    ushort* WoutT    = (ushort*)ws;                 ws += (size_t)DD * DD * 2;        // 2 MB
    ushort* query_bf = (ushort*)ws;
    float*  logitsP  = (float*)ws;                  ws += (size_t)BT * DD * 2;        // 8 MB
    ushort* WqvT     = (ushort*)ws;                 ws += (size_t)2 * DD * DD * 2;    // 4 MB
    ushort* reluq    = (ushort*)ws;                 ws += (size_t)BT * DD * 2;        // 8 MB
    ushort* vbuf     = (ushort*)ws;                 ws += (size_t)BT * DD * 2;        // 8 MB
    ushort* xbuf     = (ushort*)ws;                 ws += (size_t)BT * DD * 2;        // 8 MB

    // 0) all conversions in one launch
    convert_all<<<R4, 256, 0, stream>>>(query, query_bf, W_qv, WqvT,
                                        W_out, WoutT, W2_0, W2_1, W2T);

    // 1) qv GEMM: [4096,1024]x[1024,2048] -> reluq bf16 + v bf16 (512 blocks, 8 iters)
    {   dim3 grid(2 * DD / 128, BT / 128, 1);
        gemm_mfma<<<grid, 256, 0, stream>>>(query_bf, WqvT, DD, DD,
                                            nullptr, reluq, vbuf, 2, 0); }
    // 2) logits GEMM split-K=2: relu(q) x W2T -> logitsP (128 blocks, 4 iters)
    {   dim3 grid(NL / 128, BT / 128, KSPLIT);
        gemm_mfma<<<grid, 256, 0, stream>>>(reluq, W2T, DD, DD / KSPLIT,
                                            logitsP, nullptr, nullptr, 3, NL); }
    // 3) softmax (+partial sum) + sliding window -> xbuf bf16
    attn_window_kernel<<<256, 256, 0, stream>>>(vbuf, logitsP, scale_w, xbuf);

    // 4) out GEMM: x x WoutT -> out f32 (256 blocks, 8 iters)
    {   dim3 grid(DD / 128, BT / 128, 1);
        gemm_mfma<<<grid, 256, 0, stream>>>(xbuf, WoutT, DD, DD,
                                            out, nullptr, nullptr, 0, DD); }
}